// Round 15
// baseline (52.667 us; speedup 1.0000x reference)
//
#include <hip/hip_runtime.h>
#include <math.h>

typedef __attribute__((ext_vector_type(4))) float f32x4;
typedef __attribute__((ext_vector_type(8))) short s16x8;

__device__ __forceinline__ short f2bf_rne(float f) {
  unsigned u = __float_as_uint(f);
  unsigned r = u + 0x7FFFu + ((u >> 16) & 1u);
  return (short)(r >> 16);
}
__device__ __forceinline__ float bf2f(short b) {
  return __uint_as_float(((unsigned)(unsigned short)b) << 16);
}

#define WAIT_VMCNT(N) asm volatile("s_waitcnt vmcnt(" #N ")" ::: "memory")
#define BAR()         __builtin_amdgcn_s_barrier()
#define CFENCE()      asm volatile("" ::: "memory")
#define SCHEDB()      __builtin_amdgcn_sched_barrier(0)

__device__ __forceinline__ void gl_lds16(const void* g, void* l) {
  __builtin_amdgcn_global_load_lds(
      (const __attribute__((address_space(1))) void*)g,
      (__attribute__((address_space(3))) void*)l, 16, 0, 0);
}

// pinned 16B global load to named VGPRs, non-temporal (x is stream-once:
// keep it from evicting partials/wf in L2). Completion via manual vmcnt.
#define GLOAD4NT(D, P) \
  asm volatile("global_load_dwordx4 %0, %1, off nt" : "=&v"(D) : "v"(P))

// ---------------- W1 -> bf16 hi/lo fragment pre-pack (verified r7-r14) ----------------
// frag element j of lane l holds k = chunk*32 + (l>>4)*8 + j, col = nt*16 + (l&15)
// ws layout: slot = (chunk*4 + nt)*2 + sel (0=hi,1=lo); frag addr = (slot*64 + l)*8 ushorts
__global__ __launch_bounds__(256) void prep_w1(const float* __restrict__ W1,
                                               unsigned short* __restrict__ wf) {
  const int c   = blockIdx.x;         // k-chunk 0..39
  const int l   = threadIdx.x & 63;
  const int nt  = threadIdx.x >> 6;   // 0..3
  const int kb  = c * 32 + (l >> 4) * 8;
  const int col = nt * 16 + (l & 15);
  s16x8 hi, lo;
#pragma unroll
  for (int j = 0; j < 8; ++j) {
    float f = W1[(kb + j) * 64 + col];
    short h = f2bf_rne(f);
    hi[j] = h;
    lo[j] = f2bf_rne(f - bf2f(h));
  }
  const int slot = (c * 4 + nt) * 2;
  *(s16x8*)(wf + (size_t)(slot * 64 + l) * 8)       = hi;
  *(s16x8*)(wf + (size_t)((slot + 1) * 64 + l) * 8) = lo;
}

// ---------------- circuit macros (verified rounds 1-14) ----------------
#define APPLY_RY(BIT, C, S)                                                  \
  { _Pragma("unroll")                                                        \
    for (int i = 0; i < 16; ++i) {                                           \
      if (!(i & (BIT))) {                                                    \
        const int j = i | (BIT);                                             \
        float ar = re[i], ai = im[i], br = re[j], bi = im[j];                \
        re[i] = fmaf((C), ar, -(S) * br);                                    \
        im[i] = fmaf((C), ai, -(S) * bi);                                    \
        re[j] = fmaf((S), ar, (C) * br);                                     \
        im[j] = fmaf((S), ai, (C) * bi);                                     \
      }                                                                      \
    } }

#define APPLY_RZ(BIT, C, S)                                                  \
  { _Pragma("unroll")                                                        \
    for (int i = 0; i < 16; ++i) {                                           \
      float vr = re[i], vi = im[i];                                          \
      if (!(i & (BIT))) { re[i] = fmaf((C), vr, (S) * vi);                   \
                          im[i] = fmaf((C), vi, -(S) * vr); }                \
      else              { re[i] = fmaf((C), vr, -(S) * vi);                  \
                          im[i] = fmaf((C), vi, (S) * vr); }                 \
    } }

#define APPLY_CNOT(CB, TB)                                                   \
  { _Pragma("unroll")                                                        \
    for (int i = 0; i < 16; ++i) {                                           \
      if ((i & (CB)) && !(i & (TB))) {                                       \
        const int j = i | (TB);                                              \
        float t = re[i]; re[i] = re[j]; re[j] = t;                           \
        t = im[i]; im[i] = im[j]; im[j] = t;                                 \
      }                                                                      \
    } }

// Shared tail: reduced[4] -> statevector -> head -> logit
__device__ __forceinline__ float qfc_head(
    const float* __restrict__ red, const float* __restrict__ qw,
    const float* __restrict__ Wc1, const float* __restrict__ bc1,
    const float* __restrict__ Wc2, const float* __restrict__ bc2) {
  float re[16], im[16];
#pragma unroll
  for (int i = 0; i < 16; ++i) { re[i] = 0.f; im[i] = 0.f; }
  re[0] = 1.f;
  {
    float s0, c0; sincosf(0.5f * red[0], &s0, &c0); APPLY_RY(8, c0, s0);
    float s1, c1; sincosf(0.5f * red[1], &s1, &c1); APPLY_RY(4, c1, s1);
    float s2, c2; sincosf(0.5f * red[2], &s2, &c2); APPLY_RY(2, c2, s2);
    float s3, c3; sincosf(0.5f * red[3], &s3, &c3); APPLY_RY(1, c3, s3);
  }
  for (int lyr = 0; lyr < 3; ++lyr) {
    const float* ql = qw + lyr * 8;
    { float sn, cn; sincosf(0.5f * ql[0], &sn, &cn); APPLY_RY(8, cn, sn); }
    { float sn, cn; sincosf(0.5f * ql[1], &sn, &cn); APPLY_RZ(8, cn, sn); }
    { float sn, cn; sincosf(0.5f * ql[2], &sn, &cn); APPLY_RY(4, cn, sn); }
    { float sn, cn; sincosf(0.5f * ql[3], &sn, &cn); APPLY_RZ(4, cn, sn); }
    { float sn, cn; sincosf(0.5f * ql[4], &sn, &cn); APPLY_RY(2, cn, sn); }
    { float sn, cn; sincosf(0.5f * ql[5], &sn, &cn); APPLY_RZ(2, cn, sn); }
    { float sn, cn; sincosf(0.5f * ql[6], &sn, &cn); APPLY_RY(1, cn, sn); }
    { float sn, cn; sincosf(0.5f * ql[7], &sn, &cn); APPLY_RZ(1, cn, sn); }
    APPLY_CNOT(8, 4);
    APPLY_CNOT(4, 2);
    APPLY_CNOT(2, 1);
    APPLY_CNOT(1, 8);
  }
  float q0 = 0.f, q1 = 0.f, q2 = 0.f, q3 = 0.f;
#pragma unroll
  for (int i = 0; i < 16; ++i) {
    const float pr = fmaf(re[i], re[i], im[i] * im[i]);
    q0 += (i & 8) ? -pr : pr;
    q1 += (i & 4) ? -pr : pr;
    q2 += (i & 2) ? -pr : pr;
    q3 += (i & 1) ? -pr : pr;
  }
  float logit = bc2[0];
#pragma unroll
  for (int j = 0; j < 16; ++j) {
    float a = bc1[j];
    a = fmaf(red[0], Wc1[j],       a);
    a = fmaf(red[1], Wc1[16 + j],  a);
    a = fmaf(red[2], Wc1[32 + j],  a);
    a = fmaf(red[3], Wc1[48 + j],  a);
    a = fmaf(q0,     Wc1[64 + j],  a);
    a = fmaf(q1,     Wc1[80 + j],  a);
    a = fmaf(q2,     Wc1[96 + j],  a);
    a = fmaf(q3,     Wc1[112 + j], a);
    logit = fmaf(fmaxf(a, 0.f), Wc2[j], logit);
  }
  return logit;
}

// ============ Kernel A: split-K(5) GEMM, depth-3 pipeline, XCD-local ============
// 1280 blocks x 256 thr. bid -> (rt,kq) remapped so bid%8 == rt%8: all 5 kq
// writers of a row-tile AND its tail block share one XCD's L2 (partials stay
// L2-resident; x loads are nt so the stream doesn't evict them).
// Wave w owns rows rt*64+w*16..+16; 4 waves cooperatively stage+share B.
// LDS = 4 bufs x 8KB = 32KB (5 blocks/CU); A in a 4-set register rotation via
// pinned asm loads; prefetch distance 3; steady-state vmcnt(8); 1 barrier/chunk.
__global__ __launch_bounds__(256) void qfc_gemm(
    const float* __restrict__ x,            // [16384,1280]
    const unsigned short* __restrict__ wf,  // W1 frags (prep_w1)
    float* __restrict__ pw)                 // partials [1280][4096]
{
  __shared__ s16x8 Bs[4][512];  // 4 x 8KB B frag buffers (hi/lo)

  const int tid  = threadIdx.x;
  const int l    = tid & 63;
  const int wv   = tid >> 6;
  // ---- XCD-local remap: bid%8 == rt%8 (bijective over 1280) ----
  const int bid  = blockIdx.x;
  const int s_   = bid >> 3;               // 0..159
  const int kq   = s_ >> 5;                // 0..4
  const int rt   = (bid & 7) + ((s_ & 31) << 3);  // 0..255
  const int r0   = rt * 64;
  const int arow = l & 15;
  const int kg   = l >> 4;                 // 0..3

  // A source: lane handles row r0+wv*16+arow, k slice kq*256 + c*32 + kg*8
  const float* xrow = x + (size_t)(r0 + wv * 16 + arow) * 1280 + kq * 256 + kg * 8;
  // B source: this kq's 8 chunks contiguous in wf; this wave stages slice wv*128
  const s16x8* wfb = (const s16x8*)wf + (size_t)(kq * 8) * 512 + wv * 128 + l;

  f32x4 acc[4];
#pragma unroll
  for (int nt = 0; nt < 4; ++nt) acc[nt] = (f32x4)(0.f);

  float4 a00, a01, a10, a11, a20, a21, a30, a31;  // 4-set A rotation (set = c%4)

  // ---- prologue: stage chunks 0,1,2 -> 12 vmem ops in flight ----
  gl_lds16(wfb,             &Bs[0][wv * 128]);
  gl_lds16(wfb + 64,        &Bs[0][wv * 128 + 64]);
  GLOAD4NT(a00, xrow);
  GLOAD4NT(a01, xrow + 4);
  gl_lds16(wfb + 512,       &Bs[1][wv * 128]);
  gl_lds16(wfb + 512 + 64,  &Bs[1][wv * 128 + 64]);
  GLOAD4NT(a10, xrow + 32);
  GLOAD4NT(a11, xrow + 36);
  gl_lds16(wfb + 1024,      &Bs[2][wv * 128]);
  gl_lds16(wfb + 1024 + 64, &Bs[2][wv * 128 + 64]);
  GLOAD4NT(a20, xrow + 64);
  GLOAD4NT(a21, xrow + 68);

  // Per chunk C: vmcnt -> chunk C's 4 loads landed (8 newer stay in flight);
  // barrier (all waves' B slices present); restage buf (C+3)%4 (last read at
  // C-1, whose ds_reads completed before each wave reached this barrier);
  // cvt A(C); 12 MFMA on Bs[C%4].
#define CHUNK(C, AC0, AC1, AN0, AN1)                                          \
  {                                                                           \
    if ((C) <= 5) { WAIT_VMCNT(8); }                                          \
    else if ((C) == 6) { WAIT_VMCNT(4); }                                     \
    else { WAIT_VMCNT(0); }                                                   \
    BAR();                                                                    \
    CFENCE();                                                                 \
    SCHEDB();                                                                 \
    if ((C) + 3 < 8) {                                                        \
      const s16x8* bsrc_ = wfb + (size_t)((C) + 3) * 512;                     \
      gl_lds16(bsrc_,      &Bs[((C) + 3) & 3][wv * 128]);                     \
      gl_lds16(bsrc_ + 64, &Bs[((C) + 3) & 3][wv * 128 + 64]);                \
      GLOAD4NT(AN0, xrow + ((C) + 3) * 32);                                   \
      GLOAD4NT(AN1, xrow + ((C) + 3) * 32 + 4);                               \
    }                                                                         \
    SCHEDB();                                                                 \
    float f_[8] = {AC0.x, AC0.y, AC0.z, AC0.w, AC1.x, AC1.y, AC1.z, AC1.w};   \
    s16x8 ah_, al_;                                                           \
    _Pragma("unroll")                                                         \
    for (int j = 0; j < 8; ++j) {                                             \
      short h_ = f2bf_rne(f_[j]);                                             \
      ah_[j] = h_;                                                            \
      al_[j] = (short)(__float_as_uint(f_[j] - bf2f(h_)) >> 16);              \
    }                                                                         \
    _Pragma("unroll")                                                         \
    for (int nt = 0; nt < 4; ++nt) {                                          \
      s16x8 bh_ = Bs[(C) & 3][(nt * 2) * 64 + l];                             \
      s16x8 bl_ = Bs[(C) & 3][(nt * 2 + 1) * 64 + l];                         \
      acc[nt] = __builtin_amdgcn_mfma_f32_16x16x32_bf16(ah_, bh_, acc[nt], 0, 0, 0); \
      acc[nt] = __builtin_amdgcn_mfma_f32_16x16x32_bf16(al_, bh_, acc[nt], 0, 0, 0); \
      acc[nt] = __builtin_amdgcn_mfma_f32_16x16x32_bf16(ah_, bl_, acc[nt], 0, 0, 0); \
    }                                                                         \
  }

  CHUNK(0, a00, a01, a30, a31)
  CHUNK(1, a10, a11, a00, a01)
  CHUNK(2, a20, a21, a10, a11)
  CHUNK(3, a30, a31, a20, a21)
  CHUNK(4, a00, a01, a30, a31)
  CHUNK(5, a10, a11, a00, a01)
  CHUNK(6, a20, a21, a10, a11)
  CHUNK(7, a30, a31, a00, a01)
#undef CHUNK

  // ---- store partial: D row_local = kg*4+q, col = nt*16+arow (m89 C/D map) ----
  float* wsp = pw + (size_t)(rt * 5 + kq) * 4096;
#pragma unroll
  for (int nt = 0; nt < 4; ++nt)
    *(float4*)(wsp + (nt * 16 + arow) * 64 + wv * 16 + kg * 4) =
        make_float4(acc[nt][0], acc[nt][1], acc[nt][2], acc[nt][3]);
}

// ============ Kernel B: combine 5 partials + fused tail (r9-proven) ============
// 256 blocks x 256 threads; block rt covers samples rt*64..+64, 4 threads/sample.
// Tail block rt runs on XCD rt%8 == the XCD whose L2 holds rt's partials.
__global__ __launch_bounds__(256) void qfc_tail(
    const float* __restrict__ pw,   // partials [1280][4096], 5 per rt
    const float* __restrict__ b1, const float* __restrict__ W2,
    const float* __restrict__ b2, const float* __restrict__ qw,
    const float* __restrict__ Wc1, const float* __restrict__ bc1,
    const float* __restrict__ Wc2, const float* __restrict__ bc2,
    float* __restrict__ out) {
  const int tid = threadIdx.x;
  const int s   = tid >> 2;  // sample within tile 0..63
  const int cq  = tid & 3;   // c-quarter (16 cols)
  const int rt  = blockIdx.x;
  const float* pb = pw + (size_t)rt * 5 * 4096;

  float h4[4] = {0.f, 0.f, 0.f, 0.f};
#pragma unroll
  for (int cc = 0; cc < 16; ++cc) {
    const int c = cq * 16 + cc;
    const int o = c * 64 + s;
    float p = pb[o];
#pragma unroll
    for (int q = 1; q < 5; ++q) p += pb[q * 4096 + o];  // fixed order
    float hv = fmaxf(p + b1[c], 0.f);
    const float4 w2 = *(const float4*)(W2 + c * 4);
    h4[0] = fmaf(hv, w2.x, h4[0]);
    h4[1] = fmaf(hv, w2.y, h4[1]);
    h4[2] = fmaf(hv, w2.z, h4[2]);
    h4[3] = fmaf(hv, w2.w, h4[3]);
  }
#pragma unroll
  for (int k = 0; k < 4; ++k) {
    h4[k] += __shfl_xor(h4[k], 1);
    h4[k] += __shfl_xor(h4[k], 2);
  }

  float red[4];
#pragma unroll
  for (int k = 0; k < 4; ++k) red[k] = tanhf(h4[k] + b2[k]);

  const float logit = qfc_head(red, qw, Wc1, bc1, Wc2, bc2);
  if (cq == 0) out[rt * 64 + s] = logit;
}

// ============ Fallback: round-1 pure-VALU kernel (no ws needed) ============
#define NKT 20
__global__ __launch_bounds__(256) void qfc_fused(
    const float* __restrict__ x, const float* __restrict__ W1,
    const float* __restrict__ b1, const float* __restrict__ W2,
    const float* __restrict__ b2, const float* __restrict__ qw,
    const float* __restrict__ Wc1, const float* __restrict__ bc1,
    const float* __restrict__ Wc2, const float* __restrict__ bc2,
    float* __restrict__ out) {
  __shared__ float lds[16384];
  const int tid = threadIdx.x;
  const int lane = tid & 63;
  const int wv = tid >> 6;
  const int rg = lane >> 3;
  const int cg = lane & 7;
  const int r0 = blockIdx.x * 64;
  float acc[8][8];
#pragma unroll
  for (int i = 0; i < 8; ++i)
#pragma unroll
    for (int j = 0; j < 8; ++j) acc[i][j] = 0.f;
  const float* xrow = x + (size_t)(r0 + lane) * 1280 + wv * 16;
  const int aBase = wv * 1024;
  const int bBase = 8192 + wv * 1024;
  float4 a_st[4], b_st[4];
  auto issue_loads = [&](int kt) {
    const float* ap = xrow + kt * 64;
#pragma unroll
    for (int i = 0; i < 4; ++i) a_st[i] = *(const float4*)(ap + i * 4);
    const float* bp = W1 + kt * 4096 + wv * 1024 + lane * 4;
#pragma unroll
    for (int i = 0; i < 4; ++i) b_st[i] = *(const float4*)(bp + i * 256);
  };
  auto write_stage = [&](int buf) {
    float* A = &lds[buf * 4096 + aBase];
#pragma unroll
    for (int i = 0; i < 4; ++i) {
      float* p = A + i * 256 + lane;
      p[0] = a_st[i].x; p[64] = a_st[i].y; p[128] = a_st[i].z; p[192] = a_st[i].w;
    }
    float* Bp = &lds[buf * 4096 + bBase + lane * 4];
#pragma unroll
    for (int i = 0; i < 4; ++i) *(float4*)(Bp + i * 256) = b_st[i];
  };
  auto compute_tile = [&](int buf) {
#pragma unroll
    for (int m = 0; m < 16; ++m) {
      const float* Ak = &lds[buf * 4096 + aBase + m * 64];
      const float* Bk = &lds[buf * 4096 + bBase + m * 64];
      const float4 a0 = *(const float4*)(Ak + rg * 8);
      const float4 a1 = *(const float4*)(Ak + rg * 8 + 4);
      const float4 c0 = *(const float4*)(Bk + cg * 8);
      const float4 c1 = *(const float4*)(Bk + cg * 8 + 4);
      const float av[8] = {a0.x, a0.y, a0.z, a0.w, a1.x, a1.y, a1.z, a1.w};
      const float bv[8] = {c0.x, c0.y, c0.z, c0.w, c1.x, c1.y, c1.z, c1.w};
#pragma unroll
      for (int i = 0; i < 8; ++i)
#pragma unroll
        for (int j = 0; j < 8; ++j) acc[i][j] = fmaf(av[i], bv[j], acc[i][j]);
    }
  };
  issue_loads(0);
  write_stage(0);
  for (int kt = 0; kt < NKT; ++kt) {
    const int buf = kt & 1;
    if (kt + 1 < NKT) issue_loads(kt + 1);
    compute_tile(buf);
    if (kt + 1 < NKT) write_stage(buf ^ 1);
  }
  __syncthreads();
#pragma unroll
  for (int j = 0; j < 8; ++j) {
    const int c = cg * 8 + j;
    float* p = &lds[wv * 4096 + c * 64 + rg * 8];
    *(float4*)p = make_float4(acc[0][j], acc[1][j], acc[2][j], acc[3][j]);
    *(float4*)(p + 4) = make_float4(acc[4][j], acc[5][j], acc[6][j], acc[7][j]);
  }
  __syncthreads();
  const int s = tid >> 2;
  const int cq = tid & 3;
  float h4[4] = {0.f, 0.f, 0.f, 0.f};
#pragma unroll
  for (int cc = 0; cc < 16; ++cc) {
    const int c = cq * 16 + cc;
    const int o = c * 64 + s;
    float pp = (lds[o] + lds[4096 + o]) + (lds[8192 + o] + lds[12288 + o]);
    float hv = fmaxf(pp + b1[c], 0.f);
    const float4 w2 = *(const float4*)(W2 + c * 4);
    h4[0] = fmaf(hv, w2.x, h4[0]);
    h4[1] = fmaf(hv, w2.y, h4[1]);
    h4[2] = fmaf(hv, w2.z, h4[2]);
    h4[3] = fmaf(hv, w2.w, h4[3]);
  }
#pragma unroll
  for (int k = 0; k < 4; ++k) {
    h4[k] += __shfl_xor(h4[k], 1);
    h4[k] += __shfl_xor(h4[k], 2);
  }
  float red[4];
#pragma unroll
  for (int k = 0; k < 4; ++k) red[k] = tanhf(h4[k] + b2[k]);
  const float logit = qfc_head(red, qw, Wc1, bc1, Wc2, bc2);
  if (cq == 0) out[r0 + s] = logit;
}

extern "C" void kernel_launch(void* const* d_in, const int* in_sizes, int n_in,
                              void* d_out, int out_size, void* d_ws, size_t ws_size,
                              hipStream_t stream) {
  const float* x   = (const float*)d_in[0];
  const float* W1  = (const float*)d_in[1];
  const float* b1  = (const float*)d_in[2];
  const float* W2  = (const float*)d_in[3];
  const float* b2  = (const float*)d_in[4];
  const float* qw  = (const float*)d_in[5];
  const float* Wc1 = (const float*)d_in[6];
  const float* bc1 = (const float*)d_in[7];
  const float* Wc2 = (const float*)d_in[8];
  const float* bc2 = (const float*)d_in[9];

  const size_t WF_BYTES = 327680;                    // W1 hi/lo frags
  const size_t PW_OFF   = WF_BYTES;
  const size_t PW_BYTES = (size_t)1280 * 4096 * 4;   // 20 MB partials
  if (ws_size >= PW_OFF + PW_BYTES) {
    unsigned short* wf = (unsigned short*)d_ws;
    float* pw = (float*)((char*)d_ws + PW_OFF);
    prep_w1<<<dim3(40), dim3(256), 0, stream>>>(W1, wf);
    qfc_gemm<<<dim3(1280), dim3(256), 0, stream>>>(x, wf, pw);
    qfc_tail<<<dim3(256), dim3(256), 0, stream>>>(
        pw, b1, W2, b2, qw, Wc1, bc1, Wc2, bc2, (float*)d_out);
  } else {
    qfc_fused<<<dim3(256), dim3(256), 0, stream>>>(
        x, W1, b1, W2, b2, qw, Wc1, bc1, Wc2, bc2, (float*)d_out);
  }
}

// Round 17
// 40.333 us; speedup vs baseline: 1.3058x; 1.3058x over previous
//
#include <hip/hip_runtime.h>
#include <math.h>

typedef __attribute__((ext_vector_type(4))) float f32x4;
typedef __attribute__((ext_vector_type(8))) short s16x8;

__device__ __forceinline__ short f2bf_rne(float f) {
  unsigned u = __float_as_uint(f);
  unsigned r = u + 0x7FFFu + ((u >> 16) & 1u);
  return (short)(r >> 16);
}
__device__ __forceinline__ float bf2f(short b) {
  return __uint_as_float(((unsigned)(unsigned short)b) << 16);
}

#define WAIT_VMCNT(N) asm volatile("s_waitcnt vmcnt(" #N ")" ::: "memory")
#define SCHEDB()      __builtin_amdgcn_sched_barrier(0)

// pinned 16B global load into named VGPRs (f32x4 or s16x8 = 128-bit).
// Compiler cannot sink/reorder it; completion covered by hand-counted vmcnt.
#define GLOAD4(D, P) \
  asm volatile("global_load_dwordx4 %0, %1, off" : "=&v"(D) : "v"(P))

// ---------------- W1 -> bf16 hi/lo fragment pre-pack (verified r7-r15) ----------------
// frag element j of lane l holds k = chunk*32 + (l>>4)*8 + j, col = nt*16 + (l&15)
// ws layout: slot = (chunk*4 + nt)*2 + sel (0=hi,1=lo); frag addr = (slot*64 + l)*8 ushorts
__global__ __launch_bounds__(256) void prep_w1(const float* __restrict__ W1,
                                               unsigned short* __restrict__ wf) {
  const int c   = blockIdx.x;         // k-chunk 0..39
  const int l   = threadIdx.x & 63;
  const int nt  = threadIdx.x >> 6;   // 0..3
  const int kb  = c * 32 + (l >> 4) * 8;
  const int col = nt * 16 + (l & 15);
  s16x8 hi, lo;
#pragma unroll
  for (int j = 0; j < 8; ++j) {
    float f = W1[(kb + j) * 64 + col];
    short h = f2bf_rne(f);
    hi[j] = h;
    lo[j] = f2bf_rne(f - bf2f(h));
  }
  const int slot = (c * 4 + nt) * 2;
  *(s16x8*)(wf + (size_t)(slot * 64 + l) * 8)       = hi;
  *(s16x8*)(wf + (size_t)((slot + 1) * 64 + l) * 8) = lo;
}

// ---------------- circuit macros (verified rounds 1-15) ----------------
#define APPLY_RY(BIT, C, S)                                                  \
  { _Pragma("unroll")                                                        \
    for (int i = 0; i < 16; ++i) {                                           \
      if (!(i & (BIT))) {                                                    \
        const int j = i | (BIT);                                             \
        float ar = re[i], ai = im[i], br = re[j], bi = im[j];                \
        re[i] = fmaf((C), ar, -(S) * br);                                    \
        im[i] = fmaf((C), ai, -(S) * bi);                                    \
        re[j] = fmaf((S), ar, (C) * br);                                     \
        im[j] = fmaf((S), ai, (C) * bi);                                     \
      }                                                                      \
    } }

#define APPLY_RZ(BIT, C, S)                                                  \
  { _Pragma("unroll")                                                        \
    for (int i = 0; i < 16; ++i) {                                           \
      float vr = re[i], vi = im[i];                                          \
      if (!(i & (BIT))) { re[i] = fmaf((C), vr, (S) * vi);                   \
                          im[i] = fmaf((C), vi, -(S) * vr); }                \
      else              { re[i] = fmaf((C), vr, -(S) * vi);                  \
                          im[i] = fmaf((C), vi, (S) * vr); }                 \
    } }

#define APPLY_CNOT(CB, TB)                                                   \
  { _Pragma("unroll")                                                        \
    for (int i = 0; i < 16; ++i) {                                           \
      if ((i & (CB)) && !(i & (TB))) {                                       \
        const int j = i | (TB);                                              \
        float t = re[i]; re[i] = re[j]; re[j] = t;                           \
        t = im[i]; im[i] = im[j]; im[j] = t;                                 \
      }                                                                      \
    } }

// Shared tail: reduced[4] -> statevector -> head -> logit
__device__ __forceinline__ float qfc_head(
    const float* __restrict__ red, const float* __restrict__ qw,
    const float* __restrict__ Wc1, const float* __restrict__ bc1,
    const float* __restrict__ Wc2, const float* __restrict__ bc2) {
  float re[16], im[16];
#pragma unroll
  for (int i = 0; i < 16; ++i) { re[i] = 0.f; im[i] = 0.f; }
  re[0] = 1.f;
  {
    float s0, c0; sincosf(0.5f * red[0], &s0, &c0); APPLY_RY(8, c0, s0);
    float s1, c1; sincosf(0.5f * red[1], &s1, &c1); APPLY_RY(4, c1, s1);
    float s2, c2; sincosf(0.5f * red[2], &s2, &c2); APPLY_RY(2, c2, s2);
    float s3, c3; sincosf(0.5f * red[3], &s3, &c3); APPLY_RY(1, c3, s3);
  }
  for (int lyr = 0; lyr < 3; ++lyr) {
    const float* ql = qw + lyr * 8;
    { float sn, cn; sincosf(0.5f * ql[0], &sn, &cn); APPLY_RY(8, cn, sn); }
    { float sn, cn; sincosf(0.5f * ql[1], &sn, &cn); APPLY_RZ(8, cn, sn); }
    { float sn, cn; sincosf(0.5f * ql[2], &sn, &cn); APPLY_RY(4, cn, sn); }
    { float sn, cn; sincosf(0.5f * ql[3], &sn, &cn); APPLY_RZ(4, cn, sn); }
    { float sn, cn; sincosf(0.5f * ql[4], &sn, &cn); APPLY_RY(2, cn, sn); }
    { float sn, cn; sincosf(0.5f * ql[5], &sn, &cn); APPLY_RZ(2, cn, sn); }
    { float sn, cn; sincosf(0.5f * ql[6], &sn, &cn); APPLY_RY(1, cn, sn); }
    { float sn, cn; sincosf(0.5f * ql[7], &sn, &cn); APPLY_RZ(1, cn, sn); }
    APPLY_CNOT(8, 4);
    APPLY_CNOT(4, 2);
    APPLY_CNOT(2, 1);
    APPLY_CNOT(1, 8);
  }
  float q0 = 0.f, q1 = 0.f, q2 = 0.f, q3 = 0.f;
#pragma unroll
  for (int i = 0; i < 16; ++i) {
    const float pr = fmaf(re[i], re[i], im[i] * im[i]);
    q0 += (i & 8) ? -pr : pr;
    q1 += (i & 4) ? -pr : pr;
    q2 += (i & 2) ? -pr : pr;
    q3 += (i & 1) ? -pr : pr;
  }
  float logit = bc2[0];
#pragma unroll
  for (int j = 0; j < 16; ++j) {
    float a = bc1[j];
    a = fmaf(red[0], Wc1[j],       a);
    a = fmaf(red[1], Wc1[16 + j],  a);
    a = fmaf(red[2], Wc1[32 + j],  a);
    a = fmaf(red[3], Wc1[48 + j],  a);
    a = fmaf(q0,     Wc1[64 + j],  a);
    a = fmaf(q1,     Wc1[80 + j],  a);
    a = fmaf(q2,     Wc1[96 + j],  a);
    a = fmaf(q3,     Wc1[112 + j], a);
    logit = fmaf(fmaxf(a, 0.f), Wc2[j], logit);
  }
  return logit;
}

// ============ fused kernel: barrier-free, all-register, pinned-load pipeline ============
// R8 GEOMETRY (r16 had it wrong -> OOB fault): 1024 blocks x 256 thr.
// Block = 16 rows (rbase = blockIdx.x*16); ALL 4 waves cover those same rows;
// wave wv owns k-quarter [wv*320, +320) = 10 chunks of K=32.
// A: 4-deep reg rotation; B frags: 2-deep reg rotation (8 pinned dwordx4/chunk,
// L2-resident wf). NO LDS staging, NO barriers in the main loop, hand-counted
// vmcnt (steady 10, never 0 mid-loop). End: 16KB LDS k-partial handoff +
// wave-0 tail (r8-verified).
__global__ __launch_bounds__(256) void qfc_pinned(
    const float* __restrict__ x,            // [16384,1280]
    const unsigned short* __restrict__ wf,  // W1 frags (prep_w1)
    const float* __restrict__ b1, const float* __restrict__ W2,
    const float* __restrict__ b2, const float* __restrict__ qw,
    const float* __restrict__ Wc1, const float* __restrict__ bc1,
    const float* __restrict__ Wc2, const float* __restrict__ bc2,
    float* __restrict__ out) {
  __shared__ float lds[4096];  // k-partial handoff only (16KB)

  const int tid   = threadIdx.x;
  const int l     = tid & 63;
  const int wv    = tid >> 6;   // k-quarter owner
  const int rbase = blockIdx.x * 16;  // 16 rows per block (r8 geometry!)
  const int arow  = l & 15;
  const int kg    = l >> 4;     // 0..3

  // A source: lane handles row rbase + arow, k = wv*320 + c*32 + kg*8
  const float* xp = x + (size_t)(rbase + arow) * 1280 + wv * 320 + kg * 8;
  // B source: wave's 10 chunks contiguous in wf (chunk slot stride 512 s16x8)
  const s16x8* bw = (const s16x8*)wf + (size_t)wv * 5120 + l;

  f32x4 acc[4];
#pragma unroll
  for (int nt = 0; nt < 4; ++nt) acc[nt] = (f32x4)(0.f);

  f32x4 apf[4][2];   // A rotation, 4 deep (literal-indexed -> registers)
  s16x8 bpf[2][8];   // B rotation, 2 deep

#define ISSUE_A(SLOT, C)                       \
  { GLOAD4(apf[SLOT][0], xp + (C) * 32);       \
    GLOAD4(apf[SLOT][1], xp + (C) * 32 + 4); }
#define ISSUE_B(SLOT, C)                                   \
  { _Pragma("unroll")                                      \
    for (int q_ = 0; q_ < 8; ++q_)                         \
      GLOAD4(bpf[SLOT][q_], bw + (C) * 512 + q_ * 64); }

  // prologue: A0..A3 (8 ops), B0,B1 (16 ops) -> 24 in flight
  ISSUE_A(0, 0) ISSUE_A(1, 1) ISSUE_A(2, 2) ISSUE_A(3, 3)
  ISSUE_B(0, 0) ISSUE_B(1, 1)

  // Ledger (program order: A0..A3,B0,B1, then per chunk +A,+B):
  // C0 wait(8): completes A0-A3+B0. C1-6 wait(10): completes prior A+B pair.
  // C7 wait(8): completes A9+B7 (leaves B8). C8 wait(8): completes B8. C9: 0.
#define CHUNK(C, WN, IA, IB)                                                  \
  {                                                                           \
    WAIT_VMCNT(WN);                                                           \
    SCHEDB();                                                                 \
    float f_[8] = {apf[(C) & 3][0].x, apf[(C) & 3][0].y, apf[(C) & 3][0].z,   \
                   apf[(C) & 3][0].w, apf[(C) & 3][1].x, apf[(C) & 3][1].y,   \
                   apf[(C) & 3][1].z, apf[(C) & 3][1].w};                     \
    s16x8 ah_, al_;                                                           \
    _Pragma("unroll")                                                         \
    for (int j = 0; j < 8; ++j) {                                             \
      short h_ = f2bf_rne(f_[j]);                                             \
      ah_[j] = h_;                                                            \
      al_[j] = (short)(__float_as_uint(f_[j] - bf2f(h_)) >> 16);              \
    }                                                                         \
    _Pragma("unroll")                                                         \
    for (int nt = 0; nt < 4; ++nt) {                                          \
      acc[nt] = __builtin_amdgcn_mfma_f32_16x16x32_bf16(ah_, bpf[(C) & 1][nt * 2],     acc[nt], 0, 0, 0); \
      acc[nt] = __builtin_amdgcn_mfma_f32_16x16x32_bf16(al_, bpf[(C) & 1][nt * 2],     acc[nt], 0, 0, 0); \
      acc[nt] = __builtin_amdgcn_mfma_f32_16x16x32_bf16(ah_, bpf[(C) & 1][nt * 2 + 1], acc[nt], 0, 0, 0); \
    }                                                                         \
    SCHEDB();                                                                 \
    if (IA) ISSUE_A((C) & 3, (C) + 4)                                         \
    if (IB) ISSUE_B((C) & 1, (C) + 2)                                         \
  }

  CHUNK(0, 8,  1, 1)
  CHUNK(1, 10, 1, 1)
  CHUNK(2, 10, 1, 1)
  CHUNK(3, 10, 1, 1)
  CHUNK(4, 10, 1, 1)
  CHUNK(5, 10, 1, 1)
  CHUNK(6, 10, 0, 1)
  CHUNK(7, 8,  0, 1)
  CHUNK(8, 8,  0, 0)
  CHUNK(9, 0,  0, 0)
#undef CHUNK
#undef ISSUE_A
#undef ISSUE_B

  // ---- k-partial handoff (r8-verified): part[wv][col][row16] ----
#pragma unroll
  for (int nt = 0; nt < 4; ++nt)
    *(float4*)&lds[wv * 1024 + (nt * 16 + arow) * 16 + kg * 4] =
        make_float4(acc[nt][0], acc[nt][1], acc[nt][2], acc[nt][3]);
  __syncthreads();

  // ---- wave-0 tail: 4 threads per sample, 16 samples (r8-verified) ----
  if (tid < 64) {
    const int s  = tid >> 2;  // sample 0..15
    const int cq = tid & 3;   // c-quarter (16 cols)

    float h4[4] = {0.f, 0.f, 0.f, 0.f};
#pragma unroll
    for (int cc = 0; cc < 16; ++cc) {
      const int c = cq * 16 + cc;
      const int o = c * 16 + s;
      float p  = (lds[o] + lds[1024 + o]) + (lds[2048 + o] + lds[3072 + o]);
      float hv = fmaxf(p + b1[c], 0.f);
      const float4 w2 = *(const float4*)(W2 + c * 4);
      h4[0] = fmaf(hv, w2.x, h4[0]);
      h4[1] = fmaf(hv, w2.y, h4[1]);
      h4[2] = fmaf(hv, w2.z, h4[2]);
      h4[3] = fmaf(hv, w2.w, h4[3]);
    }
#pragma unroll
    for (int k = 0; k < 4; ++k) {
      h4[k] += __shfl_xor(h4[k], 1);
      h4[k] += __shfl_xor(h4[k], 2);
    }

    float red[4];
#pragma unroll
    for (int k = 0; k < 4; ++k) red[k] = tanhf(h4[k] + b2[k]);

    const float logit = qfc_head(red, qw, Wc1, bc1, Wc2, bc2);
    if (cq == 0) out[rbase + s] = logit;
  }
}

// ============ Fallback: round-1 pure-VALU kernel (no ws needed) ============
#define NKT 20
__global__ __launch_bounds__(256) void qfc_fused(
    const float* __restrict__ x, const float* __restrict__ W1,
    const float* __restrict__ b1, const float* __restrict__ W2,
    const float* __restrict__ b2, const float* __restrict__ qw,
    const float* __restrict__ Wc1, const float* __restrict__ bc1,
    const float* __restrict__ Wc2, const float* __restrict__ bc2,
    float* __restrict__ out) {
  __shared__ float lds[16384];
  const int tid = threadIdx.x;
  const int lane = tid & 63;
  const int wv = tid >> 6;
  const int rg = lane >> 3;
  const int cg = lane & 7;
  const int r0 = blockIdx.x * 64;
  float acc[8][8];
#pragma unroll
  for (int i = 0; i < 8; ++i)
#pragma unroll
    for (int j = 0; j < 8; ++j) acc[i][j] = 0.f;
  const float* xrow = x + (size_t)(r0 + lane) * 1280 + wv * 16;
  const int aBase = wv * 1024;
  const int bBase = 8192 + wv * 1024;
  float4 a_st[4], b_st[4];
  auto issue_loads = [&](int kt) {
    const float* ap = xrow + kt * 64;
#pragma unroll
    for (int i = 0; i < 4; ++i) a_st[i] = *(const float4*)(ap + i * 4);
    const float* bp = W1 + kt * 4096 + wv * 1024 + lane * 4;
#pragma unroll
    for (int i = 0; i < 4; ++i) b_st[i] = *(const float4*)(bp + i * 256);
  };
  auto write_stage = [&](int buf) {
    float* A = &lds[buf * 4096 + aBase];
#pragma unroll
    for (int i = 0; i < 4; ++i) {
      float* p = A + i * 256 + lane;
      p[0] = a_st[i].x; p[64] = a_st[i].y; p[128] = a_st[i].z; p[192] = a_st[i].w;
    }
    float* Bp = &lds[buf * 4096 + bBase + lane * 4];
#pragma unroll
    for (int i = 0; i < 4; ++i) *(float4*)(Bp + i * 256) = b_st[i];
  };
  auto compute_tile = [&](int buf) {
#pragma unroll
    for (int m = 0; m < 16; ++m) {
      const float* Ak = &lds[buf * 4096 + aBase + m * 64];
      const float* Bk = &lds[buf * 4096 + bBase + m * 64];
      const float4 a0 = *(const float4*)(Ak + rg * 8);
      const float4 a1 = *(const float4*)(Ak + rg * 8 + 4);
      const float4 c0 = *(const float4*)(Bk + cg * 8);
      const float4 c1 = *(const float4*)(Bk + cg * 8 + 4);
      const float av[8] = {a0.x, a0.y, a0.z, a0.w, a1.x, a1.y, a1.z, a1.w};
      const float bv[8] = {c0.x, c0.y, c0.z, c0.w, c1.x, c1.y, c1.z, c1.w};
#pragma unroll
      for (int i = 0; i < 8; ++i)
#pragma unroll
        for (int j = 0; j < 8; ++j) acc[i][j] = fmaf(av[i], bv[j], acc[i][j]);
    }
  };
  issue_loads(0);
  write_stage(0);
  for (int kt = 0; kt < NKT; ++kt) {
    const int buf = kt & 1;
    if (kt + 1 < NKT) issue_loads(kt + 1);
    compute_tile(buf);
    if (kt + 1 < NKT) write_stage(buf ^ 1);
  }
  __syncthreads();
#pragma unroll
  for (int j = 0; j < 8; ++j) {
    const int c = cg * 8 + j;
    float* p = &lds[wv * 4096 + c * 64 + rg * 8];
    *(float4*)p = make_float4(acc[0][j], acc[1][j], acc[2][j], acc[3][j]);
    *(float4*)(p + 4) = make_float4(acc[4][j], acc[5][j], acc[6][j], acc[7][j]);
  }
  __syncthreads();
  const int s = tid >> 2;
  const int cq = tid & 3;
  float h4[4] = {0.f, 0.f, 0.f, 0.f};
#pragma unroll
  for (int cc = 0; cc < 16; ++cc) {
    const int c = cq * 16 + cc;
    const int o = c * 64 + s;
    float pp = (lds[o] + lds[4096 + o]) + (lds[8192 + o] + lds[12288 + o]);
    float hv = fmaxf(pp + b1[c], 0.f);
    const float4 w2 = *(const float4*)(W2 + c * 4);
    h4[0] = fmaf(hv, w2.x, h4[0]);
    h4[1] = fmaf(hv, w2.y, h4[1]);
    h4[2] = fmaf(hv, w2.z, h4[2]);
    h4[3] = fmaf(hv, w2.w, h4[3]);
  }
#pragma unroll
  for (int k = 0; k < 4; ++k) {
    h4[k] += __shfl_xor(h4[k], 1);
    h4[k] += __shfl_xor(h4[k], 2);
  }
  float red[4];
#pragma unroll
  for (int k = 0; k < 4; ++k) red[k] = tanhf(h4[k] + b2[k]);
  const float logit = qfc_head(red, qw, Wc1, bc1, Wc2, bc2);
  if (cq == 0) out[r0 + s] = logit;
}

extern "C" void kernel_launch(void* const* d_in, const int* in_sizes, int n_in,
                              void* d_out, int out_size, void* d_ws, size_t ws_size,
                              hipStream_t stream) {
  const float* x   = (const float*)d_in[0];
  const float* W1  = (const float*)d_in[1];
  const float* b1  = (const float*)d_in[2];
  const float* W2  = (const float*)d_in[3];
  const float* b2  = (const float*)d_in[4];
  const float* qw  = (const float*)d_in[5];
  const float* Wc1 = (const float*)d_in[6];
  const float* bc1 = (const float*)d_in[7];
  const float* Wc2 = (const float*)d_in[8];
  const float* bc2 = (const float*)d_in[9];

  const size_t WF_BYTES = 327680;  // W1 hi/lo frags
  if (ws_size >= WF_BYTES) {
    unsigned short* wf = (unsigned short*)d_ws;
    prep_w1<<<dim3(40), dim3(256), 0, stream>>>(W1, wf);
    qfc_pinned<<<dim3(1024), dim3(256), 0, stream>>>(
        x, wf, b1, W2, b2, qw, Wc1, bc1, Wc2, bc2, (float*)d_out);
  } else {
    qfc_fused<<<dim3(256), dim3(256), 0, stream>>>(
        x, W1, b1, W2, b2, qw, Wc1, bc1, Wc2, bc2, (float*)d_out);
  }
}